// Round 6
// baseline (156.681 us; speedup 1.0000x reference)
//
#include <hip/hip_runtime.h>

typedef _Float16 half8_t __attribute__((ext_vector_type(8)));
typedef _Float16 half4_t __attribute__((ext_vector_type(4)));
typedef _Float16 half2_t __attribute__((ext_vector_type(2)));
typedef __fp16 fp16x2 __attribute__((ext_vector_type(2)));
typedef float f32x4 __attribute__((ext_vector_type(4)));

#define S_LEN 2048
#define D_DIM 64
#define SD (S_LEN * D_DIM)
#define BC 64
#define NKT (S_LEN / BC)   // 32 key tiles
#define LDK 72             // f16 row stride (64 + 8 pad)
#define LDO 68             // f32 row stride for epilogue

// 256 threads = 4 waves; wave w owns q rows [32w,32w+32) as two 16-q groups.
// Latency-oriented iteration: both groups' softmax phases interleaved,
// l-reduction deferred to epilogue (per-lane partials), stage+prefetch+acc
// scaling placed inside the P write->read LDS round-trip window.
__global__ __launch_bounds__(256, 2)
void fattn_kernel(const float* __restrict__ Qg, const float* __restrict__ Kg,
                  const float* __restrict__ Vg, const int* __restrict__ Mg,
                  float* __restrict__ Og) {
  __shared__ __align__(16) char smem[63488];
  // K buf0 [0,9216) K buf1 [9216,18432) V buf0 [18432,27648) V buf1 [27648,36864)
  _Float16* Psh = (_Float16*)(smem + 36864);  // 4 waves x [32 q][72] f16
  float*    Msh = (float*)(smem + 55296);     // [2048] additive mask {0,-1e30}
  float*    Osh = (float*)smem;               // [128][68] f32, epilogue reuse

  const int t = threadIdx.x;
  const int w = t >> 6;
  const int lane = t & 63;
  const int g = lane >> 4;   // quad
  const int c = lane & 15;

  // bh in low bits: all 16 q-blocks of one (b,h) hit the SAME XCD
  const int bh = blockIdx.x & 31;
  const int qt = blockIdx.x >> 5;
  const int qb = qt * 128;

  const float* Qb = Qg + (size_t)bh * SD;
  const float* Kb = Kg + (size_t)bh * SD;
  const float* Vb = Vg + (size_t)bh * SD;
  const int*   Mb = Mg + (size_t)(bh >> 3) * S_LEN;  // H = 8
  float*       Ob = Og + (size_t)bh * SD;

  // ---- stage additive mask -> LDS once: (m-1)*1e30 -> {0, -1e30} ----
  {
    int4 m0 = *(const int4*)(Mb + 8 * t);
    int4 m1 = *(const int4*)(Mb + 8 * t + 4);
    float4 f0, f1;
    f0.x = (float)(m0.x - 1) * 1e30f; f0.y = (float)(m0.y - 1) * 1e30f;
    f0.z = (float)(m0.z - 1) * 1e30f; f0.w = (float)(m0.w - 1) * 1e30f;
    f1.x = (float)(m1.x - 1) * 1e30f; f1.y = (float)(m1.y - 1) * 1e30f;
    f1.z = (float)(m1.z - 1) * 1e30f; f1.w = (float)(m1.w - 1) * 1e30f;
    *(float4*)(Msh + 8 * t) = f0;
    *(float4*)(Msh + 8 * t + 4) = f1;
  }

  // ---- Q^T B-frags for q = qb + 32w + 16h + c; fold 1/8 * log2(e) ----
  const float qscale = 0.125f * 1.44269504088896340736f;
  half8_t qf[2][2];
#pragma unroll
  for (int h = 0; h < 2; ++h) {
    const float* qp = Qb + (size_t)(qb + 32 * w + 16 * h + c) * D_DIM + 8 * g;
#pragma unroll
    for (int ks = 0; ks < 2; ++ks) {
      float4 lo = *(const float4*)(qp + 32 * ks);
      float4 hi = *(const float4*)(qp + 32 * ks + 4);
      fp16x2 p0 = __builtin_amdgcn_cvt_pkrtz(lo.x * qscale, lo.y * qscale);
      fp16x2 p1 = __builtin_amdgcn_cvt_pkrtz(lo.z * qscale, lo.w * qscale);
      fp16x2 p2 = __builtin_amdgcn_cvt_pkrtz(hi.x * qscale, hi.y * qscale);
      fp16x2 p3 = __builtin_amdgcn_cvt_pkrtz(hi.z * qscale, hi.w * qscale);
      half8_t hh;
      hh[0] = (_Float16)p0[0]; hh[1] = (_Float16)p0[1];
      hh[2] = (_Float16)p1[0]; hh[3] = (_Float16)p1[1];
      hh[4] = (_Float16)p2[0]; hh[5] = (_Float16)p2[1];
      hh[6] = (_Float16)p3[0]; hh[7] = (_Float16)p3[1];
      qf[h][ks] = hh;
    }
  }

  // ---- staging coordinates (256 threads) ----
  const int krow0 = t >> 4;   // 0..15; K row = krow0 + 16*it
  const int kc4   = t & 15;   // K float4 column
  const int vp    = t >> 3;   // V d-pair 0..31
  const int vkpl  = t & 7;    // V key-pair low; kp = vkpl + 8*kc

  float4 kr[4];
  float2 vr[8];
  auto prefetch = [&](int kb2) {
#pragma unroll
    for (int it = 0; it < 4; ++it)
      kr[it] = *(const float4*)(Kb + (size_t)(kb2 + krow0 + 16 * it) * D_DIM + kc4 * 4);
#pragma unroll
    for (int kc = 0; kc < 4; ++kc) {
      const float* vpp = Vb + (size_t)(kb2 + 2 * (vkpl + 8 * kc)) * D_DIM + 2 * vp;
      vr[2 * kc]     = *(const float2*)(vpp);
      vr[2 * kc + 1] = *(const float2*)(vpp + D_DIM);
    }
  };
  auto stage = [&](int buf) {
    _Float16* Kd = (_Float16*)(smem + 9216 * buf);
    _Float16* Vd = (_Float16*)(smem + 18432 + 9216 * buf);
#pragma unroll
    for (int it = 0; it < 4; ++it) {
      fp16x2 a  = __builtin_amdgcn_cvt_pkrtz(kr[it].x, kr[it].y);
      fp16x2 b2 = __builtin_amdgcn_cvt_pkrtz(kr[it].z, kr[it].w);
      half4_t h;
      h[0] = (_Float16)a[0]; h[1] = (_Float16)a[1];
      h[2] = (_Float16)b2[0]; h[3] = (_Float16)b2[1];
      *(half4_t*)(Kd + (krow0 + 16 * it) * LDK + kc4 * 4) = h;
    }
#pragma unroll
    for (int kc = 0; kc < 4; ++kc) {
      int kp = vkpl + 8 * kc;
      fp16x2 h0 = __builtin_amdgcn_cvt_pkrtz(vr[2 * kc].x, vr[2 * kc + 1].x);
      fp16x2 h1 = __builtin_amdgcn_cvt_pkrtz(vr[2 * kc].y, vr[2 * kc + 1].y);
      half2_t g0; g0[0] = (_Float16)h0[0]; g0[1] = (_Float16)h0[1];
      half2_t g1; g1[0] = (_Float16)h1[0]; g1[1] = (_Float16)h1[1];
      *(half2_t*)(Vd + (2 * vp) * LDK + 2 * kp) = g0;
      *(half2_t*)(Vd + (2 * vp + 1) * LDK + 2 * kp) = g1;
    }
  };

  f32x4 acc[2][4];
#pragma unroll
  for (int h = 0; h < 2; ++h)
#pragma unroll
    for (int i = 0; i < 4; ++i)
#pragma unroll
      for (int j = 0; j < 4; ++j) acc[h][i][j] = 0.f;
  float mrun[2] = {-1e30f, -1e30f};
  float lrun[2] = {0.f, 0.f};   // PER-LANE partial denominators (reduced at end)

  _Float16* Pw = Psh + w * 32 * LDK;

  // prologue: tile0 -> buf0; tile1 in flight
  prefetch(0);
  stage(0);
  prefetch(BC);
  __syncthreads();

  for (int kt = 0; kt < NKT; ++kt) {
    const int kb = kt * BC;
    const int cur = kt & 1;

    const _Float16* Kc = (const _Float16*)(smem + 9216 * cur);
    const _Float16* Vc = (const _Float16*)(smem + 18432 + 9216 * cur);

    // ---- all LDS reads up front: mask, K frags, V frags (V used late) ----
    f32x4 mvf[4];
#pragma unroll
    for (int mt = 0; mt < 4; ++mt)
      mvf[mt] = *(const f32x4*)(Msh + kb + 16 * mt + 4 * g);

    half8_t kf[4][2];
    half8_t vf[4][2];
#pragma unroll
    for (int mt = 0; mt < 4; ++mt)
#pragma unroll
      for (int ks = 0; ks < 2; ++ks) {
        kf[mt][ks] = *(half8_t*)(Kc + (16 * mt + c) * LDK + ks * 32 + 8 * g);
        vf[mt][ks] = *(half8_t*)(Vc + (16 * mt + c) * LDK + ks * 32 + 8 * g);
      }

    // ---- S^T = K . Q^T for both q-groups (K frag reused) ----
    f32x4 sT[2][4];
#pragma unroll
    for (int mt = 0; mt < 4; ++mt) {
      f32x4 z0, z1;
#pragma unroll
      for (int j = 0; j < 4; ++j) { z0[j] = 0.f; z1[j] = 0.f; }
#pragma unroll
      for (int ks = 0; ks < 2; ++ks) {
        z0 = __builtin_amdgcn_mfma_f32_16x16x32_f16(kf[mt][ks], qf[0][ks], z0, 0, 0, 0);
        z1 = __builtin_amdgcn_mfma_f32_16x16x32_f16(kf[mt][ks], qf[1][ks], z1, 0, 0, 0);
      }
      sT[0][mt] = z0;
      sT[1][mt] = z1;
    }

    // ---- mask add (reference semantics: s + (1-m)*(-1e30)) ----
#pragma unroll
    for (int h = 0; h < 2; ++h)
#pragma unroll
      for (int mt = 0; mt < 4; ++mt)
#pragma unroll
        for (int r = 0; r < 4; ++r) sT[h][mt][r] += mvf[mt][r];

    // ---- max trees (both groups), then both shfl pairs back-to-back ----
    float tmax[2];
#pragma unroll
    for (int h = 0; h < 2; ++h) {
      float tm0 = fmaxf(fmaxf(sT[h][0][0], sT[h][0][1]), fmaxf(sT[h][0][2], sT[h][0][3]));
      float tm1 = fmaxf(fmaxf(sT[h][1][0], sT[h][1][1]), fmaxf(sT[h][1][2], sT[h][1][3]));
      float tm2 = fmaxf(fmaxf(sT[h][2][0], sT[h][2][1]), fmaxf(sT[h][2][2], sT[h][2][3]));
      float tm3 = fmaxf(fmaxf(sT[h][3][0], sT[h][3][1]), fmaxf(sT[h][3][2], sT[h][3][3]));
      tmax[h] = fmaxf(fmaxf(tm0, tm1), fmaxf(tm2, tm3));
    }
    float s0 = __shfl_xor(tmax[0], 16);
    float s1 = __shfl_xor(tmax[1], 16);
    tmax[0] = fmaxf(tmax[0], s0);
    tmax[1] = fmaxf(tmax[1], s1);
    s0 = __shfl_xor(tmax[0], 32);
    s1 = __shfl_xor(tmax[1], 32);
    tmax[0] = fmaxf(tmax[0], s0);
    tmax[1] = fmaxf(tmax[1], s1);

    float mnew[2], alpha[2];
#pragma unroll
    for (int h = 0; h < 2; ++h) {
      mnew[h] = fmaxf(mrun[h], tmax[h]);
      alpha[h] = __builtin_amdgcn_exp2f(mrun[h] - mnew[h]);
      mrun[h] = mnew[h];
    }

    // ---- exps + P writes, both groups interleaved; l stays per-lane ----
#pragma unroll
    for (int h = 0; h < 2; ++h) {
      float lt = 0.f;
      _Float16* Pr = Pw + (16 * h + c) * LDK;
#pragma unroll
      for (int mt = 0; mt < 4; ++mt) {
        float pv0 = __builtin_amdgcn_exp2f(sT[h][mt][0] - mnew[h]);
        float pv1 = __builtin_amdgcn_exp2f(sT[h][mt][1] - mnew[h]);
        float pv2 = __builtin_amdgcn_exp2f(sT[h][mt][2] - mnew[h]);
        float pv3 = __builtin_amdgcn_exp2f(sT[h][mt][3] - mnew[h]);
        lt += (pv0 + pv1) + (pv2 + pv3);
        fp16x2 p01 = __builtin_amdgcn_cvt_pkrtz(pv0, pv1);
        fp16x2 p23 = __builtin_amdgcn_cvt_pkrtz(pv2, pv3);
        half4_t ph;
        ph[0] = (_Float16)p01[0]; ph[1] = (_Float16)p01[1];
        ph[2] = (_Float16)p23[0]; ph[3] = (_Float16)p23[1];
        *(half4_t*)(Pr + 16 * mt + 4 * g) = ph;  // b64 write
      }
      lrun[h] = lrun[h] * alpha[h] + lt;  // no cross-lane reduction in-loop
    }

    // ---- fill the P write->read window: acc scaling, stage, prefetch ----
#pragma unroll
    for (int h = 0; h < 2; ++h)
#pragma unroll
      for (int mt = 0; mt < 4; ++mt) {
        acc[h][mt][0] *= alpha[h]; acc[h][mt][1] *= alpha[h];
        acc[h][mt][2] *= alpha[h]; acc[h][mt][3] *= alpha[h];
      }
    if (kt < NKT - 1) stage(cur ^ 1);
    if (kt < NKT - 2) prefetch(kb + 2 * BC);

    // ---- P reads + PV MFMAs (V frags already in regs) ----
#pragma unroll
    for (int h = 0; h < 2; ++h) {
#pragma unroll
      for (int ks = 0; ks < 2; ++ks) {
        half8_t pf = *(half8_t*)(Pw + (16 * h + c) * LDK + ks * 32 + 8 * g);
#pragma unroll
        for (int mt = 0; mt < 4; ++mt)
          acc[h][mt] = __builtin_amdgcn_mfma_f32_16x16x32_f16(vf[mt][ks], pf,
                                                              acc[h][mt], 0, 0, 0);
      }
    }

    __syncthreads();  // single barrier: guards next iter's buffer swap
  }

  // ---- epilogue: reduce l across lanes ONCE, /l, transpose via LDS ----
#pragma unroll
  for (int h = 0; h < 2; ++h) {
    float l = lrun[h];
    l += __shfl_xor(l, 16);
    l += __shfl_xor(l, 32);
    float linv = 1.f / l;
#pragma unroll
    for (int mt = 0; mt < 4; ++mt)
#pragma unroll
      for (int r = 0; r < 4; ++r)
        Osh[(32 * w + 16 * h + c) * LDO + 16 * mt + 4 * g + r] = acc[h][mt][r] * linv;
  }
  __syncthreads();
  {
    int f8 = t & 7;
#pragma unroll
    for (int i = 0; i < 4; ++i) {
      int q = (t >> 3) + 32 * i;
#pragma unroll
      for (int j = 0; j < 2; ++j) {
        int c4 = f8 + 8 * j;
        f32x4 o = *(f32x4*)(Osh + q * LDO + c4 * 4);
        *(float4*)(Ob + (size_t)(qb + q) * D_DIM + c4 * 4) =
            make_float4(o.x, o.y, o.z, o.w);
      }
    }
  }
}

extern "C" void kernel_launch(void* const* d_in, const int* in_sizes, int n_in,
                              void* d_out, int out_size, void* d_ws, size_t ws_size,
                              hipStream_t stream) {
  (void)in_sizes; (void)n_in; (void)d_ws; (void)ws_size; (void)out_size;
  const float* Q = (const float*)d_in[0];
  const float* K = (const float*)d_in[1];
  const float* V = (const float*)d_in[2];
  const int*   M = (const int*)d_in[3];
  float* O = (float*)d_out;
  // grid: bh fast (XCD locality), 16 q-tiles slow
  fattn_kernel<<<dim3(32 * 16), dim3(256), 0, stream>>>(Q, K, V, M, O);
}